// Round 5
// baseline (696.550 us; speedup 1.0000x reference)
//
#include <hip/hip_runtime.h>

typedef _Float16 half8 __attribute__((ext_vector_type(8)));
typedef float floatx4 __attribute__((ext_vector_type(4)));

// async global->LDS, 16B per lane (dest = wave-uniform base + lane*16)
__device__ __forceinline__ void gl16(const _Float16* g, _Float16* l) {
    __builtin_amdgcn_global_load_lds((const __attribute__((address_space(1))) void*)g,
                                     (__attribute__((address_space(3))) void*)l, 16, 0, 0);
}

// inline-asm LDS read (kept from R4): opaque to compiler alias analysis.
// Ordering discipline (rule 18): explicit lgkmcnt + sched_barrier(0) before use.
__device__ __forceinline__ half8 dsr16(const _Float16* p) {
    half8 r;
    const __attribute__((address_space(3))) _Float16* lp =
        (const __attribute__((address_space(3))) _Float16*)p;
    asm volatile("ds_read_b128 %0, %1" : "=v"(r) : "v"(lp));
    return r;
}

// problem constants
#define Scst 2048
#define Dcst 512
#define Ucst 1024
#define Hcst 4
#define SDo 1048576LL   // S*D
#define UDo 524288LL    // U*D
#define SUo 2097152LL   // S*U
#define SSo 4194304LL   // S*S
#define USo 2097152LL   // U*S
#define SHUo 8388608LL  // S*H*U

// ---------------- LayerNorm: fp32 in -> fp16 out, one wave per row of 512 ----
__global__ __launch_bounds__(64) void ln_k(const float* __restrict__ x,
                                           const float* __restrict__ gamma,
                                           const float* __restrict__ beta,
                                           _Float16* __restrict__ xn) {
    const int D = 512;
    long long base = (long long)blockIdx.x * D;
    int lane = threadIdx.x;
    floatx4 x0 = *(const floatx4*)(x + base + lane * 8);
    floatx4 x1 = *(const floatx4*)(x + base + lane * 8 + 4);
    float f[8];
#pragma unroll
    for (int i = 0; i < 4; i++) { f[i] = x0[i]; f[4 + i] = x1[i]; }
    float s = 0.f, ss = 0.f;
#pragma unroll
    for (int i = 0; i < 8; i++) { s += f[i]; ss += f[i] * f[i]; }
#pragma unroll
    for (int off = 32; off; off >>= 1) { s += __shfl_xor(s, off); ss += __shfl_xor(ss, off); }
    float mean = s * (1.f / 512.f);
    float var = ss * (1.f / 512.f) - mean * mean;
    float rstd = rsqrtf(var + 1e-6f);
    floatx4 g0 = *(const floatx4*)(gamma + lane * 8);
    floatx4 g1 = *(const floatx4*)(gamma + lane * 8 + 4);
    floatx4 b0 = *(const floatx4*)(beta + lane * 8);
    floatx4 b1 = *(const floatx4*)(beta + lane * 8 + 4);
    half8 o;
#pragma unroll
    for (int i = 0; i < 4; i++) {
        o[i]     = (_Float16)((f[i]     - mean) * rstd * g0[i] + b0[i]);
        o[4 + i] = (_Float16)((f[4 + i] - mean) * rstd * g1[i] + b1[i]);
    }
    *(half8*)(xn + base + lane * 8) = o;
}

// ------------- Transpose + convert: fp32 [Z,R,C] -> fp16 [Z,C,R] -------------
__global__ __launch_bounds__(256) void tr_k(const float* __restrict__ in,
                                            _Float16* __restrict__ out, int R, int C) {
    __shared__ _Float16 tile[32][33];
    int tx = threadIdx.x, ty = threadIdx.y;
    long long zo = (long long)blockIdx.z * R * C;
    int r0 = blockIdx.y * 32, c0 = blockIdx.x * 32;
    for (int yy = ty; yy < 32; yy += 8)
        tile[yy][tx] = (_Float16)in[zo + (long long)(r0 + yy) * C + c0 + tx];
    __syncthreads();
    for (int yy = ty; yy < 32; yy += 8)
        out[zo + (long long)(c0 + yy) * R + r0 + tx] = tile[tx][yy];
}

// ---------------- GEMM (legacy 128x128): C[M,N] = A[M,K] * Bt[N,K]^T ---------
// Kept for the `out` GEMM and the low-ws fallback.
#define BM 128
#define BN 128
#define BK 32
__global__ __launch_bounds__(256) void gemm_bt(
    const _Float16* __restrict__ A, const _Float16* __restrict__ Bt, void* __restrict__ Cv,
    int K, int ldc, int cflags, int mode) {
    int z = blockIdx.z;
    long long offA = 0, offB = 0, offC = 0;
    switch (mode) {
        case 1:  // fast projQK: z = qk*8 + b2*4 + h
            offA = (long long)((z >> 2) & 1) * SDo;
            offB = (long long)(((z >> 3) * 4) + (z & 3)) * UDo;
            offC = (long long)(((z >> 3) * 8) + ((z & 3) * 2) + ((z >> 2) & 1)) * SUo;
            break;
        case 2:  // fast scores: z = h*2 + b2
            offA = (long long)z * SUo; offB = (long long)z * SUo; offC = (long long)z * SSo;
            break;
        case 3:  // fast projV: z = h*2 + b2
            offA = (long long)(z >> 1) * UDo; offB = (long long)(z & 1) * SDo;
            offC = (long long)z * USo;
            break;
        case 4:  // fast PV: z = h*2 + b2
            offA = (long long)z * SSo; offB = (long long)z * USo;
            offC = (long long)(z & 1) * SHUo + (long long)(z >> 1) * Ucst;
            break;
        case 6:  // fallback projQK: z = qk*4 + h
            offB = (long long)(z & 7) * UDo; offC = (long long)z * SUo;
            break;
        case 7:  // fallback projV: z = h
            offA = (long long)(z & 3) * UDo; offC = (long long)z * USo;
            break;
        default: break;
    }
    const _Float16* Ab = A + offA;
    const _Float16* Bb = Bt + offB;

    int gx = gridDim.x, gy = gridDim.y;
    int nb = gx * gy;
    int lin = blockIdx.y * gx + blockIdx.x;
    int mIdx, nIdx;
    if (((nb & 7) == 0) && ((gx & 3) == 0)) {
        int chunk = nb >> 3;
        int vid = (lin >> 3) + chunk * (lin & 7);
        int panelH = gy * 4;
        int panel = vid / panelH;
        int rem = vid - panel * panelH;
        mIdx = rem >> 2;
        nIdx = (panel << 2) + (rem & 3);
    } else { mIdx = blockIdx.y; nIdx = blockIdx.x; }
    int m0 = mIdx * BM, n0 = nIdx * BN;

    if ((cflags & 4) && n0 > m0 + (BM - 1)) return;
    int kend = (cflags & 8) ? min(K, m0 + BM) : K;

    __shared__ _Float16 As[2][BM * BK];
    __shared__ _Float16 Bs[2][BN * BK];

    int t = threadIdx.x;
    int srow = t >> 2;
    int scol = (t & 3) * 8;
    int lane = t & 63, w = t >> 6;
    int wm = (w >> 1) * 64, wn = (w & 1) * 64;
    int lm = lane & 15, lk = (lane >> 4) * 8;

    floatx4 acc[4][4];
#pragma unroll
    for (int i = 0; i < 4; i++)
#pragma unroll
        for (int j = 0; j < 4; j++) acc[i][j] = floatx4{0.f, 0.f, 0.f, 0.f};

    const _Float16* ga0 = Ab + (long long)(m0 + srow) * K + scol;
    const _Float16* ga1 = Ab + (long long)(m0 + 64 + srow) * K + scol;
    const _Float16* gb0 = Bb + (long long)(n0 + srow) * K + scol;
    const _Float16* gb1 = Bb + (long long)(n0 + 64 + srow) * K + scol;

    int nIter = kend / BK;
    gl16(ga0, &As[0][t * 8]);
    gl16(ga1, &As[0][2048 + t * 8]);
    gl16(gb0, &Bs[0][t * 8]);
    gl16(gb1, &Bs[0][2048 + t * 8]);

    for (int it = 0; it < nIter; it++) {
        __syncthreads();
        int cur = it & 1;
        half8 af[4], bfr[4];
#pragma unroll
        for (int i = 0; i < 4; i++) af[i] = *(const half8*)&As[cur][(wm + i * 16 + lm) * BK + lk];
#pragma unroll
        for (int j = 0; j < 4; j++) bfr[j] = *(const half8*)&Bs[cur][(wn + j * 16 + lm) * BK + lk];
        if (it + 1 < nIter) {
            int nk = (it + 1) * BK;
            int nxt = cur ^ 1;
            gl16(ga0 + nk, &As[nxt][t * 8]);
            gl16(ga1 + nk, &As[nxt][2048 + t * 8]);
            gl16(gb0 + nk, &Bs[nxt][t * 8]);
            gl16(gb1 + nk, &Bs[nxt][2048 + t * 8]);
        }
#pragma unroll
        for (int i = 0; i < 4; i++)
#pragma unroll
            for (int j = 0; j < 4; j++)
                acc[i][j] = __builtin_amdgcn_mfma_f32_16x16x32_f16(af[i], bfr[j], acc[i][j], 0, 0, 0);
    }

    int cr = (lane >> 4) * 4;
    int cc = lm;
    bool outf32 = (cflags & 1) != 0;
#pragma unroll
    for (int i = 0; i < 4; i++) {
#pragma unroll
        for (int j = 0; j < 4; j++) {
            int rr = m0 + wm + i * 16 + cr;
            int nn = n0 + wn + j * 16 + cc;
#pragma unroll
            for (int r2 = 0; r2 < 4; r2++) {
                long long idx = (long long)(rr + r2) * ldc + nn + offC;
                float val = acc[i][j][r2];
                if (outf32) ((float*)Cv)[idx] = val;
                else ((_Float16*)Cv)[idx] = (_Float16)val;
            }
        }
    }
}

// ============ 256x256 8-wave GEMM, R5: 2 phases/K-tile, 1 barrier/phase =====
// Sync-density reduction vs R1/R4 (which paid 8 barriers + 4 LDS drains per
// K-tile at ~12.5k cyc/K-tile, MfmaUtil 17%):
//  * one phase per kslice: 12 ds_reads -> gate -> barrier -> lgkmcnt(4) ->
//    16 MFMA -> lgkmcnt(0) -> 16 MFMA  (last 4 reads serviced UNDER MFMAs)
//  * ONE barrier per phase. Safe because staging is issued AFTER the MFMA
//    cluster: any wave staging region R has passed the phase barrier, and
//    every wave's reads of R's old contents completed (its lgkmcnt(0))
//    before it arrived at that barrier. Stage targets are always buffer-
//    disjoint from the phase's own read regions ((tt+1,ks1)/(tt+2,ks0) vs
//    (tt,ks)).
//  * counted gates: steady vmcnt(4) per phase (each phase's gate retires the
//    region the NEXT phase reads; 1 stage-pair in flight behind it), tail 0;
//    prologue vmcnt(8). Never a mid-loop full drain while staging continues.
// Requires M,N%256==0, K%64==0, NT>=2 (all call sites satisfy; min NT=4).
__global__ __launch_bounds__(512, 2) void gemm_bt256(
    const _Float16* __restrict__ A, const _Float16* __restrict__ Bt, void* __restrict__ Cv,
    int K, int ldc, int cflags, int mode) {
    int z = blockIdx.z;
    long long offA = 0, offB = 0, offC = 0;
    switch (mode) {
        case 1:
            offA = (long long)((z >> 2) & 1) * SDo;
            offB = (long long)(((z >> 3) * 4) + (z & 3)) * UDo;
            offC = (long long)(((z >> 3) * 8) + ((z & 3) * 2) + ((z >> 2) & 1)) * SUo;
            break;
        case 2:
            offA = (long long)z * SUo; offB = (long long)z * SUo; offC = (long long)z * SSo;
            break;
        case 3:
            offA = (long long)(z >> 1) * UDo; offB = (long long)(z & 1) * SDo;
            offC = (long long)z * USo;
            break;
        case 4:
            offA = (long long)z * SSo; offB = (long long)z * USo;
            offC = (long long)(z & 1) * SHUo + (long long)(z >> 1) * Ucst;
            break;
        default: break;
    }
    const _Float16* Ab = A + offA;
    const _Float16* Bb = Bt + offB;

    // bijective XCD-chunk swizzle (m204): contiguous wg ranges per XCD
    int gx = gridDim.x;
    int nwg = gx * gridDim.y;
    int lin = blockIdx.y * gx + blockIdx.x;
    int q8 = nwg >> 3, r8 = nwg & 7;
    int xcd = lin & 7, sub8 = lin >> 3;
    int wg = (xcd < r8 ? xcd * (q8 + 1) : r8 * (q8 + 1) + (xcd - r8) * q8) + sub8;
    int m0 = (wg / gx) * 256, n0 = (wg % gx) * 256;

    if ((cflags & 4) && n0 > m0 + 255) return;  // fully-masked causal tile
    int kend = (cflags & 8) ? min(K, m0 + 256) : K;
    int NT = kend >> 6;  // 64-wide K-tiles (NT >= 4 at all call sites)

    __shared__ _Float16 As2[2][2][8192];  // [buf][kslice][256r x 32c] swizzled
    __shared__ _Float16 Bs2[2][2][8192];

    int t = threadIdx.x;
    int lane = t & 63, w = t >> 6;
    int wm = (w >> 2) * 128, wn = (w & 3) * 64;  // 2x4 wave grid, 128x64/wave
    int lm = lane & 15, ls = lane >> 4;
    int sw8 = ((ls ^ ((lm >> 1) & 3)) << 3);  // T2: 16B-slot xor (0-conflict form)

    // staging: thread t covers region row (t>>2)+128j, logical col 8*((t&3)^((t>>3)&3))
    long long stoff = (long long)(t >> 2) * K + (((t & 3) ^ ((t >> 3) & 3)) << 3);
    const _Float16* gA = Ab + (long long)m0 * K + stoff;
    const _Float16* gB = Bb + (long long)n0 * K + stoff;
    long long rowK = 128LL * K;
    int ldd = t * 8;

    floatx4 acc[8][4];
#pragma unroll
    for (int i = 0; i < 8; i++)
#pragma unroll
        for (int j = 0; j < 4; j++) acc[i][j] = floatx4{0.f, 0.f, 0.f, 0.f};

#define STGA(v, ks) { const _Float16* s_ = gA + (((v) << 6) + ((ks) << 5)); \
        gl16(s_, &As2[(v) & 1][ks][ldd]); gl16(s_ + rowK, &As2[(v) & 1][ks][4096 + ldd]); }
#define STGB(v, ks) { const _Float16* s_ = gB + (((v) << 6) + ((ks) << 5)); \
        gl16(s_, &Bs2[(v) & 1][ks][ldd]); gl16(s_ + rowK, &Bs2[(v) & 1][ks][4096 + ldd]); }
#define RDA(mm, ks) dsr16(&As2[cur][ks][(wm + (mm) * 16 + lm) * 32 + sw8])
#define RDB(nn, ks) dsr16(&Bs2[cur][ks][(wn + (nn) * 16 + lm) * 32 + sw8])
#define MFMAH(m0_, m1_) \
    _Pragma("unroll") for (int mm = (m0_); mm < (m1_); mm++) \
    _Pragma("unroll") for (int nn = 0; nn < 4; nn++) \
        acc[mm][nn] = __builtin_amdgcn_mfma_f32_16x16x32_f16( \
            af[mm], bf[nn], acc[mm][nn], 0, 0, 0);

    // prologue: (0,ks0),(0,ks1),(1,ks0) = 12 loads; gate retires (0,ks0)
    STGA(0, 0) STGB(0, 0) STGA(0, 1) STGB(0, 1) STGA(1, 0) STGB(1, 0)
    asm volatile("s_waitcnt vmcnt(8)" ::: "memory");
    __builtin_amdgcn_s_barrier();

    for (int tt = 0; tt < NT; tt++) {
        int cur = tt & 1;
        half8 af[8], bf[4];
        bool more = (tt + 1 < NT);
        // ---------------- PH0 : kslice 0 ----------------
        bf[0] = RDB(0, 0); bf[1] = RDB(1, 0); bf[2] = RDB(2, 0); bf[3] = RDB(3, 0);
        af[0] = RDA(0, 0); af[1] = RDA(1, 0); af[2] = RDA(2, 0); af[3] = RDA(3, 0);
        af[4] = RDA(4, 0); af[5] = RDA(5, 0); af[6] = RDA(6, 0); af[7] = RDA(7, 0);
        if (more) asm volatile("s_waitcnt vmcnt(4)" ::: "memory");  // (tt,ks1) ready
        else      asm volatile("s_waitcnt vmcnt(0)" ::: "memory");
        __builtin_amdgcn_s_barrier();
        asm volatile("s_waitcnt lgkmcnt(4)" ::: "memory");  // bf+af[0..3] done
        __builtin_amdgcn_sched_barrier(0);
        __builtin_amdgcn_s_setprio(1);
        MFMAH(0, 4)
        asm volatile("s_waitcnt lgkmcnt(0)" ::: "memory");  // af[4..7] done (under MFMA)
        __builtin_amdgcn_sched_barrier(0);
        MFMAH(4, 8)
        __builtin_amdgcn_s_setprio(0);
        if (more) { STGA(tt + 1, 1) STGB(tt + 1, 1) }  // stage AFTER mfma: race-free
        // ---------------- PH1 : kslice 1 ----------------
        bf[0] = RDB(0, 1); bf[1] = RDB(1, 1); bf[2] = RDB(2, 1); bf[3] = RDB(3, 1);
        af[0] = RDA(0, 1); af[1] = RDA(1, 1); af[2] = RDA(2, 1); af[3] = RDA(3, 1);
        af[4] = RDA(4, 1); af[5] = RDA(5, 1); af[6] = RDA(6, 1); af[7] = RDA(7, 1);
        if (more) asm volatile("s_waitcnt vmcnt(4)" ::: "memory");  // (tt+1,ks0) ready
        else      asm volatile("s_waitcnt vmcnt(0)" ::: "memory");
        __builtin_amdgcn_s_barrier();
        asm volatile("s_waitcnt lgkmcnt(4)" ::: "memory");
        __builtin_amdgcn_sched_barrier(0);
        __builtin_amdgcn_s_setprio(1);
        MFMAH(0, 4)
        asm volatile("s_waitcnt lgkmcnt(0)" ::: "memory");
        __builtin_amdgcn_sched_barrier(0);
        MFMAH(4, 8)
        __builtin_amdgcn_s_setprio(0);
        if (tt + 2 < NT) { STGA(tt + 2, 0) STGB(tt + 2, 0) }
    }

    // epilogue: C/D layout col=lane&15, row=(lane>>4)*4+reg (m89-verified)
    int cr = ls * 4, cc = lm;
    bool outf32 = (cflags & 1) != 0;
#pragma unroll
    for (int i = 0; i < 8; i++) {
#pragma unroll
        for (int j = 0; j < 4; j++) {
            int rr = m0 + wm + i * 16 + cr;
            int nn = n0 + wn + j * 16 + cc;
#pragma unroll
            for (int r2 = 0; r2 < 4; r2++) {
                long long idx = (long long)(rr + r2) * ldc + nn + offC;
                float val = acc[i][j][r2];
                if (outf32) ((float*)Cv)[idx] = val;
                else ((_Float16*)Cv)[idx] = (_Float16)val;
            }
        }
    }
#undef STGA
#undef STGB
#undef RDA
#undef RDB
#undef MFMAH
}

// ------- Causal softmax, in-place fp16, rows batched over (z',seq) -----------
__global__ __launch_bounds__(256) void softmax_h(_Float16* __restrict__ sc, int S) {
    int wid = threadIdx.x >> 6, lane = threadIdx.x & 63;
    int idx = blockIdx.x * 4 + wid;
    int r = idx & (S - 1);
    _Float16* srow = sc + (long long)idx * S;
    int nc = r >> 9;
    float v[32];
    float mx = -3.0e38f;
    for (int c = 0; c <= nc; c++) {
        half8 hv = *(half8*)(srow + lane * 8 + c * 512);
#pragma unroll
        for (int i = 0; i < 8; i++) {
            int n = lane * 8 + c * 512 + i;
            float s = (n <= r) ? (float)hv[i] : -3.0e38f;
            v[c * 8 + i] = s; mx = fmaxf(mx, s);
        }
    }
#pragma unroll
    for (int off = 32; off; off >>= 1) mx = fmaxf(mx, __shfl_xor(mx, off));
    float sum = 0.f;
    for (int c = 0; c <= nc; c++)
#pragma unroll
        for (int i = 0; i < 8; i++) {
            int n = lane * 8 + c * 512 + i;
            float e = (n <= r) ? __expf(v[c * 8 + i] - mx) : 0.f;
            v[c * 8 + i] = e; sum += e;
        }
#pragma unroll
    for (int off = 32; off; off >>= 1) sum += __shfl_xor(sum, off);
    float inv = 1.f / sum;
    for (int c = 0; c <= nc; c++) {
        half8 o;
#pragma unroll
        for (int i = 0; i < 8; i++) o[i] = (_Float16)(v[c * 8 + i] * inv);
        *(half8*)(srow + lane * 8 + c * 512) = o;
    }
}

extern "C" void kernel_launch(void* const* d_in, const int* in_sizes, int n_in,
                              void* d_out, int out_size, void* d_ws, size_t ws_size,
                              hipStream_t stream) {
    const int B = 4, S = 2048, D = 512, H = 4, U = 1024;
    const float* x     = (const float*)d_in[0];
    const float* gamma = (const float*)d_in[1];
    const float* beta  = (const float*)d_in[2];
    const float* Wq    = (const float*)d_in[3];
    const float* Wk    = (const float*)d_in[4];
    const float* Wv    = (const float*)d_in[5];
    const float* Wout  = (const float*)d_in[6];
    float* out = (float*)d_out;

    char* ws = (char*)d_ws;
    const size_t MiB = 1ull << 20;
    const long long SD = SDo, UD = UDo, SU = SUo, US = USo;

    // W regions must stay adjacent (projQK offB spans WqT..WkT).
    _Float16* xn  = (_Float16*)(ws + 0);         //  8 MiB [B*S, D]
    _Float16* WqT = (_Float16*)(ws + 8  * MiB);  //  4 MiB [H, U, D]
    _Float16* WkT = (_Float16*)(ws + 12 * MiB);  //  4 MiB (adjacent!)
    _Float16* WvT = (_Float16*)(ws + 16 * MiB);  //  4 MiB
    _Float16* WoT = (_Float16*)(ws + 20 * MiB);  //  4 MiB [D, H*U]

    tr_k<<<dim3(U / 32, D / 32, H), dim3(32, 8), 0, stream>>>(Wq, WqT, D, U);
    tr_k<<<dim3(U / 32, D / 32, H), dim3(32, 8), 0, stream>>>(Wk, WkT, D, U);
    tr_k<<<dim3(U / 32, D / 32, H), dim3(32, 8), 0, stream>>>(Wv, WvT, D, U);
    tr_k<<<dim3(D / 32, (H * U) / 32, 1), dim3(32, 8), 0, stream>>>(Wout, WoT, H * U, D);
    ln_k<<<B * S, 64, 0, stream>>>(x, gamma, beta, xn);

    if (ws_size >= 168 * MiB) {
        // ---- pair-batched fast path, peak 152 MiB ----
        _Float16* qk  = (_Float16*)(ws + 24 * MiB);
        _Float16* kk  = qk + 8 * SU;
        _Float16* sc  = (_Float16*)(ws + 88 * MiB);
        _Float16* vt  = qk;
        _Float16* cat = kk;

        for (int p = 0; p < 2; p++) {
            const _Float16* xnp = xn + (long long)p * 2 * SD;
            float* outp = out + (long long)p * 2 * SD;
            // a. projQK: z = qk*8+b2*4+h (16) ; M=S,N=U,K=D
            gemm_bt256<<<dim3(U / 256, S / 256, 16), 512, 0, stream>>>(xnp, WqT, qk, D, U, 0, 1);
            // b. scores: z = h*2+b2 (8) ; M=S,N=S,K=U ; causal skip
            gemm_bt256<<<dim3(S / 256, S / 256, 8), 512, 0, stream>>>(qk, kk, sc, U, S, 4, 2);
            // c. softmax over 8*S rows
            softmax_h<<<8 * S / 4, 256, 0, stream>>>(sc, S);
            // d. projV into q-space: z = h*2+b2 ; M=U,N=S,K=D
            gemm_bt256<<<dim3(S / 256, U / 256, 8), 512, 0, stream>>>(WvT, xnp, vt, D, S, 0, 3);
            // e. PV into k-space: z = h*2+b2 ; M=S,N=U,K=S, kend=m0+256
            gemm_bt256<<<dim3(U / 256, S / 256, 8), 512, 0, stream>>>(sc, vt, cat, S, H * U, 8, 4);
            // f. out pair: M=2S, N=D, K=H*U, fp32 (legacy kernel)
            gemm_bt<<<dim3(D / 128, 2 * S / 128, 1), 256, 0, stream>>>(cat, WoT, outp,
                H * U, D, 1, 0);
        }
    } else {
        // ---- fallback: 96 MiB per-batch (R7 structure) ----
        _Float16* qb   = (_Float16*)(ws + 24 * MiB);
        _Float16* vTb  = (_Float16*)(ws + 56 * MiB);
        _Float16* catb = (_Float16*)(ws + 72 * MiB);
        _Float16* sc   = (_Float16*)(ws + 88 * MiB);

        for (int b = 0; b < B; b++) {
            const _Float16* xnb = xn + (long long)b * SD;
            gemm_bt<<<dim3(U / 128, S / 128, 2 * H), 256, 0, stream>>>(xnb, WqT, qb, D, U, 0, 6);
            gemm_bt<<<dim3(S / 128, U / 128, H), 256, 0, stream>>>(WvT, xnb, vTb, D, S, 0, 7);
            for (int h = 0; h < H; h++) {
                gemm_bt<<<dim3(S / 128, S / 128, 1), 256, 0, stream>>>(qb + (long long)h * SU,
                    qb + (long long)(H + h) * SU, sc, U, S, 4, 0);
                softmax_h<<<S / 4, 256, 0, stream>>>(sc, S);
                gemm_bt<<<dim3(U / 128, S / 128, 1), 256, 0, stream>>>(sc,
                    vTb + (long long)h * US, (void*)(catb + (long long)h * U), S, H * U, 8, 0);
            }
            gemm_bt<<<dim3(D / 128, S / 128, 1), 256, 0, stream>>>(catb, WoT,
                (void*)(out + (long long)b * SD), H * U, D, 1, 0);
        }
    }
}

// Round 6
// 681.413 us; speedup vs baseline: 1.0222x; 1.0222x over previous
//
#include <hip/hip_runtime.h>

typedef _Float16 half8 __attribute__((ext_vector_type(8)));
typedef float floatx4 __attribute__((ext_vector_type(4)));

// async global->LDS, 16B per lane (dest = wave-uniform base + lane*16)
__device__ __forceinline__ void gl16(const _Float16* g, _Float16* l) {
    __builtin_amdgcn_global_load_lds((const __attribute__((address_space(1))) void*)g,
                                     (__attribute__((address_space(3))) void*)l, 16, 0, 0);
}

// problem constants
#define Scst 2048
#define Dcst 512
#define Ucst 1024
#define Hcst 4
#define SDo 1048576LL   // S*D
#define UDo 524288LL    // U*D
#define SUo 2097152LL   // S*U
#define SSo 4194304LL   // S*S
#define USo 2097152LL   // U*S
#define SHUo 8388608LL  // S*H*U

// ---------------- LayerNorm: fp32 in -> fp16 out, one wave per row of 512 ----
__global__ __launch_bounds__(64) void ln_k(const float* __restrict__ x,
                                           const float* __restrict__ gamma,
                                           const float* __restrict__ beta,
                                           _Float16* __restrict__ xn) {
    const int D = 512;
    long long base = (long long)blockIdx.x * D;
    int lane = threadIdx.x;
    floatx4 x0 = *(const floatx4*)(x + base + lane * 8);
    floatx4 x1 = *(const floatx4*)(x + base + lane * 8 + 4);
    float f[8];
#pragma unroll
    for (int i = 0; i < 4; i++) { f[i] = x0[i]; f[4 + i] = x1[i]; }
    float s = 0.f, ss = 0.f;
#pragma unroll
    for (int i = 0; i < 8; i++) { s += f[i]; ss += f[i] * f[i]; }
#pragma unroll
    for (int off = 32; off; off >>= 1) { s += __shfl_xor(s, off); ss += __shfl_xor(ss, off); }
    float mean = s * (1.f / 512.f);
    float var = ss * (1.f / 512.f) - mean * mean;
    float rstd = rsqrtf(var + 1e-6f);
    floatx4 g0 = *(const floatx4*)(gamma + lane * 8);
    floatx4 g1 = *(const floatx4*)(gamma + lane * 8 + 4);
    floatx4 b0 = *(const floatx4*)(beta + lane * 8);
    floatx4 b1 = *(const floatx4*)(beta + lane * 8 + 4);
    half8 o;
#pragma unroll
    for (int i = 0; i < 4; i++) {
        o[i]     = (_Float16)((f[i]     - mean) * rstd * g0[i] + b0[i]);
        o[4 + i] = (_Float16)((f[4 + i] - mean) * rstd * g1[i] + b1[i]);
    }
    *(half8*)(xn + base + lane * 8) = o;
}

// ------------- Transpose + convert: fp32 [Z,R,C] -> fp16 [Z,C,R] -------------
__global__ __launch_bounds__(256) void tr_k(const float* __restrict__ in,
                                            _Float16* __restrict__ out, int R, int C) {
    __shared__ _Float16 tile[32][33];
    int tx = threadIdx.x, ty = threadIdx.y;
    long long zo = (long long)blockIdx.z * R * C;
    int r0 = blockIdx.y * 32, c0 = blockIdx.x * 32;
    for (int yy = ty; yy < 32; yy += 8)
        tile[yy][tx] = (_Float16)in[zo + (long long)(r0 + yy) * C + c0 + tx];
    __syncthreads();
    for (int yy = ty; yy < 32; yy += 8)
        out[zo + (long long)(c0 + yy) * R + r0 + tx] = tile[tx][yy];
}

// ---------------- GEMM (legacy 128x128): C[M,N] = A[M,K] * Bt[N,K]^T ---------
// Kept for the `out` GEMM and the low-ws fallback.
#define BM 128
#define BN 128
#define BK 32
__global__ __launch_bounds__(256) void gemm_bt(
    const _Float16* __restrict__ A, const _Float16* __restrict__ Bt, void* __restrict__ Cv,
    int K, int ldc, int cflags, int mode) {
    int z = blockIdx.z;
    long long offA = 0, offB = 0, offC = 0;
    switch (mode) {
        case 1:  // fast projQK: z = qk*8 + b2*4 + h
            offA = (long long)((z >> 2) & 1) * SDo;
            offB = (long long)(((z >> 3) * 4) + (z & 3)) * UDo;
            offC = (long long)(((z >> 3) * 8) + ((z & 3) * 2) + ((z >> 2) & 1)) * SUo;
            break;
        case 2:  // fast scores: z = h*2 + b2
            offA = (long long)z * SUo; offB = (long long)z * SUo; offC = (long long)z * SSo;
            break;
        case 3:  // fast projV: z = h*2 + b2
            offA = (long long)(z >> 1) * UDo; offB = (long long)(z & 1) * SDo;
            offC = (long long)z * USo;
            break;
        case 4:  // fast PV: z = h*2 + b2
            offA = (long long)z * SSo; offB = (long long)z * USo;
            offC = (long long)(z & 1) * SHUo + (long long)(z >> 1) * Ucst;
            break;
        case 6:  // fallback projQK: z = qk*4 + h
            offB = (long long)(z & 7) * UDo; offC = (long long)z * SUo;
            break;
        case 7:  // fallback projV: z = h
            offA = (long long)(z & 3) * UDo; offC = (long long)z * USo;
            break;
        default: break;
    }
    const _Float16* Ab = A + offA;
    const _Float16* Bb = Bt + offB;

    int gx = gridDim.x, gy = gridDim.y;
    int nb = gx * gy;
    int lin = blockIdx.y * gx + blockIdx.x;
    int mIdx, nIdx;
    if (((nb & 7) == 0) && ((gx & 3) == 0)) {
        int chunk = nb >> 3;
        int vid = (lin >> 3) + chunk * (lin & 7);
        int panelH = gy * 4;
        int panel = vid / panelH;
        int rem = vid - panel * panelH;
        mIdx = rem >> 2;
        nIdx = (panel << 2) + (rem & 3);
    } else { mIdx = blockIdx.y; nIdx = blockIdx.x; }
    int m0 = mIdx * BM, n0 = nIdx * BN;

    if ((cflags & 4) && n0 > m0 + (BM - 1)) return;
    int kend = (cflags & 8) ? min(K, m0 + BM) : K;

    __shared__ _Float16 As[2][BM * BK];
    __shared__ _Float16 Bs[2][BN * BK];

    int t = threadIdx.x;
    int srow = t >> 2;
    int scol = (t & 3) * 8;
    int lane = t & 63, w = t >> 6;
    int wm = (w >> 1) * 64, wn = (w & 1) * 64;
    int lm = lane & 15, lk = (lane >> 4) * 8;

    floatx4 acc[4][4];
#pragma unroll
    for (int i = 0; i < 4; i++)
#pragma unroll
        for (int j = 0; j < 4; j++) acc[i][j] = floatx4{0.f, 0.f, 0.f, 0.f};

    const _Float16* ga0 = Ab + (long long)(m0 + srow) * K + scol;
    const _Float16* ga1 = Ab + (long long)(m0 + 64 + srow) * K + scol;
    const _Float16* gb0 = Bb + (long long)(n0 + srow) * K + scol;
    const _Float16* gb1 = Bb + (long long)(n0 + 64 + srow) * K + scol;

    int nIter = kend / BK;
    gl16(ga0, &As[0][t * 8]);
    gl16(ga1, &As[0][2048 + t * 8]);
    gl16(gb0, &Bs[0][t * 8]);
    gl16(gb1, &Bs[0][2048 + t * 8]);

    for (int it = 0; it < nIter; it++) {
        __syncthreads();
        int cur = it & 1;
        half8 af[4], bfr[4];
#pragma unroll
        for (int i = 0; i < 4; i++) af[i] = *(const half8*)&As[cur][(wm + i * 16 + lm) * BK + lk];
#pragma unroll
        for (int j = 0; j < 4; j++) bfr[j] = *(const half8*)&Bs[cur][(wn + j * 16 + lm) * BK + lk];
        if (it + 1 < nIter) {
            int nk = (it + 1) * BK;
            int nxt = cur ^ 1;
            gl16(ga0 + nk, &As[nxt][t * 8]);
            gl16(ga1 + nk, &As[nxt][2048 + t * 8]);
            gl16(gb0 + nk, &Bs[nxt][t * 8]);
            gl16(gb1 + nk, &Bs[nxt][2048 + t * 8]);
        }
#pragma unroll
        for (int i = 0; i < 4; i++)
#pragma unroll
            for (int j = 0; j < 4; j++)
                acc[i][j] = __builtin_amdgcn_mfma_f32_16x16x32_f16(af[i], bfr[j], acc[i][j], 0, 0, 0);
    }

    int cr = (lane >> 4) * 4;
    int cc = lm;
    bool outf32 = (cflags & 1) != 0;
#pragma unroll
    for (int i = 0; i < 4; i++) {
#pragma unroll
        for (int j = 0; j < 4; j++) {
            int rr = m0 + wm + i * 16 + cr;
            int nn = n0 + wn + j * 16 + cc;
#pragma unroll
            for (int r2 = 0; r2 < 4; r2++) {
                long long idx = (long long)(rr + r2) * ldc + nn + offC;
                float val = acc[i][j][r2];
                if (outf32) ((float*)Cv)[idx] = val;
                else ((_Float16*)Cv)[idx] = (_Float16)val;
            }
        }
    }
}

// ======== 256x256 8-wave GEMM, R6: compiler-scheduled phases (no walls) ======
// R5 ledger kept: 2 phases/K-tile, 1 barrier/phase, counted vmcnt(4) gates,
// exact tails, stage placed right AFTER the barrier (earliest legal point:
// region's last readers all retired before any wave passed that barrier).
// R6 change: plain C++ LDS reads + plain MFMA builtins, NO sched_barrier(0),
// NO lgkmcnt asm. The register dep ds_read->MFMA makes rule-18 hoisting
// impossible; the compiler emits fine-grained lgkmcnt (m97-style) and is free
// to interleave next-phase ds_reads / staging / addr-VALU into the current
// MFMA cluster (m196: this fine interleave is the lever).
// Epilogue: acc -> LDS (reuse of the 128 KiB staging space, chunk-XOR
// swizzled) -> fully coalesced 16B/lane row-contiguous stores (fp16 only;
// all fast-path call sites are fp16).
// Requires M,N%256==0, K%64==0, NT>=2 (all call sites satisfy; min NT=4).
__global__ __launch_bounds__(512, 2) void gemm_bt256(
    const _Float16* __restrict__ A, const _Float16* __restrict__ Bt, void* __restrict__ Cv,
    int K, int ldc, int cflags, int mode) {
    int z = blockIdx.z;
    long long offA = 0, offB = 0, offC = 0;
    switch (mode) {
        case 1:
            offA = (long long)((z >> 2) & 1) * SDo;
            offB = (long long)(((z >> 3) * 4) + (z & 3)) * UDo;
            offC = (long long)(((z >> 3) * 8) + ((z & 3) * 2) + ((z >> 2) & 1)) * SUo;
            break;
        case 2:
            offA = (long long)z * SUo; offB = (long long)z * SUo; offC = (long long)z * SSo;
            break;
        case 3:
            offA = (long long)(z >> 1) * UDo; offB = (long long)(z & 1) * SDo;
            offC = (long long)z * USo;
            break;
        case 4:
            offA = (long long)z * SSo; offB = (long long)z * USo;
            offC = (long long)(z & 1) * SHUo + (long long)(z >> 1) * Ucst;
            break;
        default: break;
    }
    const _Float16* Ab = A + offA;
    const _Float16* Bb = Bt + offB;

    // bijective XCD-chunk swizzle (m204): contiguous wg ranges per XCD
    int gx = gridDim.x;
    int nwg = gx * gridDim.y;
    int lin = blockIdx.y * gx + blockIdx.x;
    int q8 = nwg >> 3, r8 = nwg & 7;
    int xcd = lin & 7, sub8 = lin >> 3;
    int wg = (xcd < r8 ? xcd * (q8 + 1) : r8 * (q8 + 1) + (xcd - r8) * q8) + sub8;
    int m0 = (wg / gx) * 256, n0 = (wg % gx) * 256;

    if ((cflags & 4) && n0 > m0 + 255) return;  // fully-masked causal tile
    int kend = (cflags & 8) ? min(K, m0 + 256) : K;
    int NT = kend >> 6;  // 64-wide K-tiles (NT >= 4 at all call sites)

    // single flat 128 KiB LDS: staging regions during loop, C tile in epilogue
    __shared__ _Float16 SH[65536];
#define ASX(b, k, i) SH[((b) << 14) + ((k) << 13) + (i)]
#define BSX(b, k, i) SH[32768 + ((b) << 14) + ((k) << 13) + (i)]

    int t = threadIdx.x;
    int lane = t & 63, w = t >> 6;
    int wm = (w >> 2) * 128, wn = (w & 3) * 64;  // 2x4 wave grid, 128x64/wave
    int lm = lane & 15, ls = lane >> 4;
    int sw8 = ((ls ^ ((lm >> 1) & 3)) << 3);  // T2: 16B-slot xor (0-conflict form)

    // staging: thread t covers region row (t>>2)+128j, logical col 8*((t&3)^((t>>3)&3))
    long long stoff = (long long)(t >> 2) * K + (((t & 3) ^ ((t >> 3) & 3)) << 3);
    const _Float16* gA = Ab + (long long)m0 * K + stoff;
    const _Float16* gB = Bb + (long long)n0 * K + stoff;
    long long rowK = 128LL * K;
    int ldd = t * 8;

    floatx4 acc[8][4];
#pragma unroll
    for (int i = 0; i < 8; i++)
#pragma unroll
        for (int j = 0; j < 4; j++) acc[i][j] = floatx4{0.f, 0.f, 0.f, 0.f};

#define STGA(v, ks) { const _Float16* s_ = gA + (((v) << 6) + ((ks) << 5)); \
        gl16(s_, &ASX((v) & 1, ks, ldd)); gl16(s_ + rowK, &ASX((v) & 1, ks, 4096 + ldd)); }
#define STGB(v, ks) { const _Float16* s_ = gB + (((v) << 6) + ((ks) << 5)); \
        gl16(s_, &BSX((v) & 1, ks, ldd)); gl16(s_ + rowK, &BSX((v) & 1, ks, 4096 + ldd)); }
#define RDA(mm, ks) (*(const half8*)&ASX(cur, ks, (wm + (mm) * 16 + lm) * 32 + sw8))
#define RDB(nn, ks) (*(const half8*)&BSX(cur, ks, (wn + (nn) * 16 + lm) * 32 + sw8))
#define MFMA32() \
    _Pragma("unroll") for (int mm = 0; mm < 8; mm++) \
    _Pragma("unroll") for (int nn = 0; nn < 4; nn++) \
        acc[mm][nn] = __builtin_amdgcn_mfma_f32_16x16x32_f16( \
            af[mm], bf[nn], acc[mm][nn], 0, 0, 0);

    // prologue: (0,ks0),(0,ks1),(1,ks0) = 12 loads; gate retires (0,ks0)
    STGA(0, 0) STGB(0, 0) STGA(0, 1) STGB(0, 1) STGA(1, 0) STGB(1, 0)
    asm volatile("s_waitcnt vmcnt(8)" ::: "memory");
    __builtin_amdgcn_s_barrier();

    for (int tt = 0; tt < NT; tt++) {
        int cur = tt & 1;
        bool more = (tt + 1 < NT);
        {   // ---------------- PH0 : kslice 0 ----------------
            half8 af[8], bf[4];
            bf[0] = RDB(0, 0); bf[1] = RDB(1, 0); bf[2] = RDB(2, 0); bf[3] = RDB(3, 0);
            af[0] = RDA(0, 0); af[1] = RDA(1, 0); af[2] = RDA(2, 0); af[3] = RDA(3, 0);
            af[4] = RDA(4, 0); af[5] = RDA(5, 0); af[6] = RDA(6, 0); af[7] = RDA(7, 0);
            if (more) asm volatile("s_waitcnt vmcnt(4)" ::: "memory");  // (tt,ks1) ready
            else      asm volatile("s_waitcnt vmcnt(0)" ::: "memory");
            __builtin_amdgcn_s_barrier();
            if (more) { STGA(tt + 1, 1) STGB(tt + 1, 1) }  // earliest legal issue
            __builtin_amdgcn_s_setprio(1);
            MFMA32()
            __builtin_amdgcn_s_setprio(0);
        }
        {   // ---------------- PH1 : kslice 1 ----------------
            half8 af[8], bf[4];
            bf[0] = RDB(0, 1); bf[1] = RDB(1, 1); bf[2] = RDB(2, 1); bf[3] = RDB(3, 1);
            af[0] = RDA(0, 1); af[1] = RDA(1, 1); af[2] = RDA(2, 1); af[3] = RDA(3, 1);
            af[4] = RDA(4, 1); af[5] = RDA(5, 1); af[6] = RDA(6, 1); af[7] = RDA(7, 1);
            if (more) asm volatile("s_waitcnt vmcnt(4)" ::: "memory");  // (tt+1,ks0) ready
            else      asm volatile("s_waitcnt vmcnt(0)" ::: "memory");
            __builtin_amdgcn_s_barrier();
            if (tt + 2 < NT) { STGA(tt + 2, 0) STGB(tt + 2, 0) }
            __builtin_amdgcn_s_setprio(1);
            MFMA32()
            __builtin_amdgcn_s_setprio(0);
        }
    }

    // ---- epilogue: acc -> LDS (chunk-XOR swizzle) -> coalesced 16B stores ----
    // C/D layout: col=lane&15, row=(lane>>4)*4+reg (m89-verified)
    __builtin_amdgcn_s_barrier();  // all loop LDS reads retired on all waves
    int cr = ls * 4;
#pragma unroll
    for (int i = 0; i < 8; i++) {
#pragma unroll
        for (int j = 0; j < 4; j++) {
#pragma unroll
            for (int r2 = 0; r2 < 4; r2++) {
                int row = wm + i * 16 + cr + r2;
                int col = wn + j * 16 + lm;
                SH[row * 256 + (col ^ ((row & 3) << 3))] = (_Float16)acc[i][j][r2];
            }
        }
    }
    __builtin_amdgcn_s_barrier();
    _Float16* Ch = (_Float16*)Cv;
    int cchunk = t & 31;          // 32 chunks of 8 halves = one 256-col row
    int rbase = t >> 5;           // 16 rows per iteration
#pragma unroll
    for (int it = 0; it < 16; it++) {
        int r = rbase + it * 16;
        half8 v = *(const half8*)&SH[r * 256 + ((cchunk ^ (r & 3)) << 3)];
        *(half8*)&Ch[(long long)(m0 + r) * ldc + n0 + (cchunk << 3) + offC] = v;
    }
#undef STGA
#undef STGB
#undef RDA
#undef RDB
#undef MFMA32
#undef ASX
#undef BSX
}

// ------- Causal softmax, in-place fp16, rows batched over (z',seq) -----------
__global__ __launch_bounds__(256) void softmax_h(_Float16* __restrict__ sc, int S) {
    int wid = threadIdx.x >> 6, lane = threadIdx.x & 63;
    int idx = blockIdx.x * 4 + wid;
    int r = idx & (S - 1);
    _Float16* srow = sc + (long long)idx * S;
    int nc = r >> 9;
    float v[32];
    float mx = -3.0e38f;
    for (int c = 0; c <= nc; c++) {
        half8 hv = *(half8*)(srow + lane * 8 + c * 512);
#pragma unroll
        for (int i = 0; i < 8; i++) {
            int n = lane * 8 + c * 512 + i;
            float s = (n <= r) ? (float)hv[i] : -3.0e38f;
            v[c * 8 + i] = s; mx = fmaxf(mx, s);
        }
    }
#pragma unroll
    for (int off = 32; off; off >>= 1) mx = fmaxf(mx, __shfl_xor(mx, off));
    float sum = 0.f;
    for (int c = 0; c <= nc; c++)
#pragma unroll
        for (int i = 0; i < 8; i++) {
            int n = lane * 8 + c * 512 + i;
            float e = (n <= r) ? __expf(v[c * 8 + i] - mx) : 0.f;
            v[c * 8 + i] = e; sum += e;
        }
#pragma unroll
    for (int off = 32; off; off >>= 1) sum += __shfl_xor(sum, off);
    float inv = 1.f / sum;
    for (int c = 0; c <= nc; c++) {
        half8 o;
#pragma unroll
        for (int i = 0; i < 8; i++) o[i] = (_Float16)(v[c * 8 + i] * inv);
        *(half8*)(srow + lane * 8 + c * 512) = o;
    }
}

extern "C" void kernel_launch(void* const* d_in, const int* in_sizes, int n_in,
                              void* d_out, int out_size, void* d_ws, size_t ws_size,
                              hipStream_t stream) {
    const int B = 4, S = 2048, D = 512, H = 4, U = 1024;
    const float* x     = (const float*)d_in[0];
    const float* gamma = (const float*)d_in[1];
    const float* beta  = (const float*)d_in[2];
    const float* Wq    = (const float*)d_in[3];
    const float* Wk    = (const float*)d_in[4];
    const float* Wv    = (const float*)d_in[5];
    const float* Wout  = (const float*)d_in[6];
    float* out = (float*)d_out;

    char* ws = (char*)d_ws;
    const size_t MiB = 1ull << 20;
    const long long SD = SDo, UD = UDo, SU = SUo, US = USo;

    // W regions must stay adjacent (projQK offB spans WqT..WkT).
    _Float16* xn  = (_Float16*)(ws + 0);         //  8 MiB [B*S, D]
    _Float16* WqT = (_Float16*)(ws + 8  * MiB);  //  4 MiB [H, U, D]
    _Float16* WkT = (_Float16*)(ws + 12 * MiB);  //  4 MiB (adjacent!)
    _Float16* WvT = (_Float16*)(ws + 16 * MiB);  //  4 MiB
    _Float16* WoT = (_Float16*)(ws + 20 * MiB);  //  4 MiB [D, H*U]

    tr_k<<<dim3(U / 32, D / 32, H), dim3(32, 8), 0, stream>>>(Wq, WqT, D, U);
    tr_k<<<dim3(U / 32, D / 32, H), dim3(32, 8), 0, stream>>>(Wk, WkT, D, U);
    tr_k<<<dim3(U / 32, D / 32, H), dim3(32, 8), 0, stream>>>(Wv, WvT, D, U);
    tr_k<<<dim3(D / 32, (H * U) / 32, 1), dim3(32, 8), 0, stream>>>(Wout, WoT, H * U, D);
    ln_k<<<B * S, 64, 0, stream>>>(x, gamma, beta, xn);

    if (ws_size >= 168 * MiB) {
        // ---- pair-batched fast path, peak 152 MiB ----
        _Float16* qk  = (_Float16*)(ws + 24 * MiB);
        _Float16* kk  = qk + 8 * SU;
        _Float16* sc  = (_Float16*)(ws + 88 * MiB);
        _Float16* vt  = qk;
        _Float16* cat = kk;

        for (int p = 0; p < 2; p++) {
            const _Float16* xnp = xn + (long long)p * 2 * SD;
            float* outp = out + (long long)p * 2 * SD;
            // a. projQK: z = qk*8+b2*4+h (16) ; M=S,N=U,K=D
            gemm_bt256<<<dim3(U / 256, S / 256, 16), 512, 0, stream>>>(xnp, WqT, qk, D, U, 0, 1);
            // b. scores: z = h*2+b2 (8) ; M=S,N=S,K=U ; causal skip
            gemm_bt256<<<dim3(S / 256, S / 256, 8), 512, 0, stream>>>(qk, kk, sc, U, S, 4, 2);
            // c. softmax over 8*S rows
            softmax_h<<<8 * S / 4, 256, 0, stream>>>(sc, S);
            // d. projV into q-space: z = h*2+b2 ; M=U,N=S,K=D
            gemm_bt256<<<dim3(S / 256, U / 256, 8), 512, 0, stream>>>(WvT, xnp, vt, D, S, 0, 3);
            // e. PV into k-space: z = h*2+b2 ; M=S,N=U,K=S, kend=m0+256
            gemm_bt256<<<dim3(U / 256, S / 256, 8), 512, 0, stream>>>(sc, vt, cat, S, H * U, 8, 4);
            // f. out pair: M=2S, N=D, K=H*U, fp32 (legacy kernel)
            gemm_bt<<<dim3(D / 128, 2 * S / 128, 1), 256, 0, stream>>>(cat, WoT, outp,
                H * U, D, 1, 0);
        }
    } else {
        // ---- fallback: 96 MiB per-batch (R7 structure) ----
        _Float16* qb   = (_Float16*)(ws + 24 * MiB);
        _Float16* vTb  = (_Float16*)(ws + 56 * MiB);
        _Float16* catb = (_Float16*)(ws + 72 * MiB);
        _Float16* sc   = (_Float16*)(ws + 88 * MiB);

        for (int b = 0; b < B; b++) {
            const _Float16* xnb = xn + (long long)b * SD;
            gemm_bt<<<dim3(U / 128, S / 128, 2 * H), 256, 0, stream>>>(xnb, WqT, qb, D, U, 0, 6);
            gemm_bt<<<dim3(S / 128, U / 128, H), 256, 0, stream>>>(WvT, xnb, vTb, D, S, 0, 7);
            for (int h = 0; h < H; h++) {
                gemm_bt<<<dim3(S / 128, S / 128, 1), 256, 0, stream>>>(qb + (long long)h * SU,
                    qb + (long long)(H + h) * SU, sc, U, S, 4, 0);
                softmax_h<<<S / 4, 256, 0, stream>>>(sc, S);
                gemm_bt<<<dim3(U / 128, S / 128, 1), 256, 0, stream>>>(sc,
                    vTb + (long long)h * US, (void*)(catb + (long long)h * U), S, H * U, 8, 0);
            }
            gemm_bt<<<dim3(D / 128, S / 128, 1), 256, 0, stream>>>(catb, WoT,
                (void*)(out + (long long)b * SD), H * U, D, 1, 0);
        }
    }
}

// Round 7
// 606.278 us; speedup vs baseline: 1.1489x; 1.1239x over previous
//
#include <hip/hip_runtime.h>

typedef _Float16 half8 __attribute__((ext_vector_type(8)));
typedef float floatx4 __attribute__((ext_vector_type(4)));

// async global->LDS, 16B per lane (dest = wave-uniform base + lane*16)
__device__ __forceinline__ void gl16(const _Float16* g, _Float16* l) {
    __builtin_amdgcn_global_load_lds((const __attribute__((address_space(1))) void*)g,
                                     (__attribute__((address_space(3))) void*)l, 16, 0, 0);
}

// problem constants
#define Scst 2048
#define Dcst 512
#define Ucst 1024
#define Hcst 4
#define SDo 1048576LL   // S*D
#define UDo 524288LL    // U*D
#define SUo 2097152LL   // S*U
#define SSo 4194304LL   // S*S
#define USo 2097152LL   // U*S
#define SHUo 8388608LL  // S*H*U

// ---------------- LayerNorm: fp32 in -> fp16 out, one wave per row of 512 ----
__global__ __launch_bounds__(64) void ln_k(const float* __restrict__ x,
                                           const float* __restrict__ gamma,
                                           const float* __restrict__ beta,
                                           _Float16* __restrict__ xn) {
    const int D = 512;
    long long base = (long long)blockIdx.x * D;
    int lane = threadIdx.x;
    floatx4 x0 = *(const floatx4*)(x + base + lane * 8);
    floatx4 x1 = *(const floatx4*)(x + base + lane * 8 + 4);
    float f[8];
#pragma unroll
    for (int i = 0; i < 4; i++) { f[i] = x0[i]; f[4 + i] = x1[i]; }
    float s = 0.f, ss = 0.f;
#pragma unroll
    for (int i = 0; i < 8; i++) { s += f[i]; ss += f[i] * f[i]; }
#pragma unroll
    for (int off = 32; off; off >>= 1) { s += __shfl_xor(s, off); ss += __shfl_xor(ss, off); }
    float mean = s * (1.f / 512.f);
    float var = ss * (1.f / 512.f) - mean * mean;
    float rstd = rsqrtf(var + 1e-6f);
    floatx4 g0 = *(const floatx4*)(gamma + lane * 8);
    floatx4 g1 = *(const floatx4*)(gamma + lane * 8 + 4);
    floatx4 b0 = *(const floatx4*)(beta + lane * 8);
    floatx4 b1 = *(const floatx4*)(beta + lane * 8 + 4);
    half8 o;
#pragma unroll
    for (int i = 0; i < 4; i++) {
        o[i]     = (_Float16)((f[i]     - mean) * rstd * g0[i] + b0[i]);
        o[4 + i] = (_Float16)((f[4 + i] - mean) * rstd * g1[i] + b1[i]);
    }
    *(half8*)(xn + base + lane * 8) = o;
}

// ------------- Transpose + convert: fp32 [Z,R,C] -> fp16 [Z,C,R] -------------
__global__ __launch_bounds__(256) void tr_k(const float* __restrict__ in,
                                            _Float16* __restrict__ out, int R, int C) {
    __shared__ _Float16 tile[32][33];
    int tx = threadIdx.x, ty = threadIdx.y;
    long long zo = (long long)blockIdx.z * R * C;
    int r0 = blockIdx.y * 32, c0 = blockIdx.x * 32;
    for (int yy = ty; yy < 32; yy += 8)
        tile[yy][tx] = (_Float16)in[zo + (long long)(r0 + yy) * C + c0 + tx];
    __syncthreads();
    for (int yy = ty; yy < 32; yy += 8)
        out[zo + (long long)(c0 + yy) * R + r0 + tx] = tile[tx][yy];
}

// ---------------- GEMM (legacy 128x128): C[M,N] = A[M,K] * Bt[N,K]^T ---------
// ldab = row stride of A and Bt (== K except split-K mode 8).
// mode 8: split-K out-GEMM: z = k-chunk, offA/offB = z*1024 (col offset),
//         offC = z*SUo into fp32 partial buffer; ldab = H*U = 4096.
#define BM 128
#define BN 128
#define BK 32
__global__ __launch_bounds__(256) void gemm_bt(
    const _Float16* __restrict__ A, const _Float16* __restrict__ Bt, void* __restrict__ Cv,
    int K, int ldc, int cflags, int mode, int ldab) {
    int z = blockIdx.z;
    long long offA = 0, offB = 0, offC = 0;
    switch (mode) {
        case 6:  // fallback projQK: z = qk*4 + h
            offB = (long long)(z & 7) * UDo; offC = (long long)z * SUo;
            break;
        case 7:  // fallback projV: z = h
            offA = (long long)(z & 3) * UDo; offC = (long long)z * USo;
            break;
        case 8:  // split-K out: z = k-chunk of 1024
            offA = (long long)z * 1024; offB = (long long)z * 1024;
            offC = (long long)z * SUo;
            break;
        default: break;
    }
    const _Float16* Ab = A + offA;
    const _Float16* Bb = Bt + offB;

    int gx = gridDim.x, gy = gridDim.y;
    int nb = gx * gy;
    int lin = blockIdx.y * gx + blockIdx.x;
    int mIdx, nIdx;
    if (((nb & 7) == 0) && ((gx & 3) == 0)) {
        int chunk = nb >> 3;
        int vid = (lin >> 3) + chunk * (lin & 7);
        int panelH = gy * 4;
        int panel = vid / panelH;
        int rem = vid - panel * panelH;
        mIdx = rem >> 2;
        nIdx = (panel << 2) + (rem & 3);
    } else { mIdx = blockIdx.y; nIdx = blockIdx.x; }
    int m0 = mIdx * BM, n0 = nIdx * BN;

    if ((cflags & 4) && n0 > m0 + (BM - 1)) return;
    int kend = (cflags & 8) ? min(K, m0 + BM) : K;

    __shared__ _Float16 As[2][BM * BK];
    __shared__ _Float16 Bs[2][BN * BK];

    int t = threadIdx.x;
    int srow = t >> 2;
    int scol = (t & 3) * 8;
    int lane = t & 63, w = t >> 6;
    int wm = (w >> 1) * 64, wn = (w & 1) * 64;
    int lm = lane & 15, lk = (lane >> 4) * 8;

    floatx4 acc[4][4];
#pragma unroll
    for (int i = 0; i < 4; i++)
#pragma unroll
        for (int j = 0; j < 4; j++) acc[i][j] = floatx4{0.f, 0.f, 0.f, 0.f};

    const _Float16* ga0 = Ab + (long long)(m0 + srow) * ldab + scol;
    const _Float16* ga1 = Ab + (long long)(m0 + 64 + srow) * ldab + scol;
    const _Float16* gb0 = Bb + (long long)(n0 + srow) * ldab + scol;
    const _Float16* gb1 = Bb + (long long)(n0 + 64 + srow) * ldab + scol;

    int nIter = kend / BK;
    gl16(ga0, &As[0][t * 8]);
    gl16(ga1, &As[0][2048 + t * 8]);
    gl16(gb0, &Bs[0][t * 8]);
    gl16(gb1, &Bs[0][2048 + t * 8]);

    for (int it = 0; it < nIter; it++) {
        __syncthreads();
        int cur = it & 1;
        half8 af[4], bfr[4];
#pragma unroll
        for (int i = 0; i < 4; i++) af[i] = *(const half8*)&As[cur][(wm + i * 16 + lm) * BK + lk];
#pragma unroll
        for (int j = 0; j < 4; j++) bfr[j] = *(const half8*)&Bs[cur][(wn + j * 16 + lm) * BK + lk];
        if (it + 1 < nIter) {
            int nk = (it + 1) * BK;
            int nxt = cur ^ 1;
            gl16(ga0 + nk, &As[nxt][t * 8]);
            gl16(ga1 + nk, &As[nxt][2048 + t * 8]);
            gl16(gb0 + nk, &Bs[nxt][t * 8]);
            gl16(gb1 + nk, &Bs[nxt][2048 + t * 8]);
        }
#pragma unroll
        for (int i = 0; i < 4; i++)
#pragma unroll
            for (int j = 0; j < 4; j++)
                acc[i][j] = __builtin_amdgcn_mfma_f32_16x16x32_f16(af[i], bfr[j], acc[i][j], 0, 0, 0);
    }

    int cr = (lane >> 4) * 4;
    int cc = lm;
    bool outf32 = (cflags & 1) != 0;
#pragma unroll
    for (int i = 0; i < 4; i++) {
#pragma unroll
        for (int j = 0; j < 4; j++) {
            int rr = m0 + wm + i * 16 + cr;
            int nn = n0 + wn + j * 16 + cc;
#pragma unroll
            for (int r2 = 0; r2 < 4; r2++) {
                long long idx = (long long)(rr + r2) * ldc + nn + offC;
                float val = acc[i][j][r2];
                if (outf32) ((float*)Cv)[idx] = val;
                else ((_Float16*)Cv)[idx] = (_Float16)val;
            }
        }
    }
}

// ---------- split-K reduce: out[i] = sum_{c<4} part[c*n + i], float4 --------
__global__ __launch_bounds__(256) void redk(const float* __restrict__ part,
                                            float* __restrict__ o, int n4) {
    long long stride = (long long)gridDim.x * 256;
    for (long long i = blockIdx.x * 256 + threadIdx.x; i < n4; i += stride) {
        floatx4 s = *(const floatx4*)(part + i * 4);
#pragma unroll
        for (int c = 1; c < 4; c++) {
            floatx4 v = *(const floatx4*)(part + (long long)c * n4 * 4 + i * 4);
            s[0] += v[0]; s[1] += v[1]; s[2] += v[2]; s[3] += v[3];
        }
        *(floatx4*)(o + i * 4) = s;
    }
}

// ======== 256x256 8-wave GEMM (R6 best): 2 phases/K-tile, 1 barrier/phase ====
// Counted vmcnt(4) gates, exact tails, stage right after the barrier, plain
// C++ LDS reads (compiler emits fine lgkmcnt), LDS-staged coalesced epilogue.
// Requires M,N%256==0, K%64==0, NT>=2 (all call sites satisfy; min NT=4).
__global__ __launch_bounds__(512, 2) void gemm_bt256(
    const _Float16* __restrict__ A, const _Float16* __restrict__ Bt, void* __restrict__ Cv,
    int K, int ldc, int cflags, int mode) {
    int z = blockIdx.z;
    long long offA = 0, offB = 0, offC = 0;
    switch (mode) {
        case 1:
            offA = (long long)((z >> 2) & 1) * SDo;
            offB = (long long)(((z >> 3) * 4) + (z & 3)) * UDo;
            offC = (long long)(((z >> 3) * 8) + ((z & 3) * 2) + ((z >> 2) & 1)) * SUo;
            break;
        case 2:
            offA = (long long)z * SUo; offB = (long long)z * SUo; offC = (long long)z * SSo;
            break;
        case 3:
            offA = (long long)(z >> 1) * UDo; offB = (long long)(z & 1) * SDo;
            offC = (long long)z * USo;
            break;
        case 4:
            offA = (long long)z * SSo; offB = (long long)z * USo;
            offC = (long long)(z & 1) * SHUo + (long long)(z >> 1) * Ucst;
            break;
        default: break;
    }
    const _Float16* Ab = A + offA;
    const _Float16* Bb = Bt + offB;

    // bijective XCD-chunk swizzle (m204): contiguous wg ranges per XCD
    int gx = gridDim.x;
    int nwg = gx * gridDim.y;
    int lin = blockIdx.y * gx + blockIdx.x;
    int q8 = nwg >> 3, r8 = nwg & 7;
    int xcd = lin & 7, sub8 = lin >> 3;
    int wg = (xcd < r8 ? xcd * (q8 + 1) : r8 * (q8 + 1) + (xcd - r8) * q8) + sub8;
    int m0 = (wg / gx) * 256, n0 = (wg % gx) * 256;

    if ((cflags & 4) && n0 > m0 + 255) return;  // fully-masked causal tile
    int kend = (cflags & 8) ? min(K, m0 + 256) : K;
    int NT = kend >> 6;  // 64-wide K-tiles (NT >= 4 at all call sites)

    // single flat 128 KiB LDS: staging regions during loop, C tile in epilogue
    __shared__ _Float16 SH[65536];
#define ASX(b, k, i) SH[((b) << 14) + ((k) << 13) + (i)]
#define BSX(b, k, i) SH[32768 + ((b) << 14) + ((k) << 13) + (i)]

    int t = threadIdx.x;
    int lane = t & 63, w = t >> 6;
    int wm = (w >> 2) * 128, wn = (w & 3) * 64;  // 2x4 wave grid, 128x64/wave
    int lm = lane & 15, ls = lane >> 4;
    int sw8 = ((ls ^ ((lm >> 1) & 3)) << 3);  // T2: 16B-slot xor (0-conflict form)

    // staging: thread t covers region row (t>>2)+128j, logical col 8*((t&3)^((t>>3)&3))
    long long stoff = (long long)(t >> 2) * K + (((t & 3) ^ ((t >> 3) & 3)) << 3);
    const _Float16* gA = Ab + (long long)m0 * K + stoff;
    const _Float16* gB = Bb + (long long)n0 * K + stoff;
    long long rowK = 128LL * K;
    int ldd = t * 8;

    floatx4 acc[8][4];
#pragma unroll
    for (int i = 0; i < 8; i++)
#pragma unroll
        for (int j = 0; j < 4; j++) acc[i][j] = floatx4{0.f, 0.f, 0.f, 0.f};

#define STGA(v, ks) { const _Float16* s_ = gA + (((v) << 6) + ((ks) << 5)); \
        gl16(s_, &ASX((v) & 1, ks, ldd)); gl16(s_ + rowK, &ASX((v) & 1, ks, 4096 + ldd)); }
#define STGB(v, ks) { const _Float16* s_ = gB + (((v) << 6) + ((ks) << 5)); \
        gl16(s_, &BSX((v) & 1, ks, ldd)); gl16(s_ + rowK, &BSX((v) & 1, ks, 4096 + ldd)); }
#define RDA(mm, ks) (*(const half8*)&ASX(cur, ks, (wm + (mm) * 16 + lm) * 32 + sw8))
#define RDB(nn, ks) (*(const half8*)&BSX(cur, ks, (wn + (nn) * 16 + lm) * 32 + sw8))
#define MFMA32() \
    _Pragma("unroll") for (int mm = 0; mm < 8; mm++) \
    _Pragma("unroll") for (int nn = 0; nn < 4; nn++) \
        acc[mm][nn] = __builtin_amdgcn_mfma_f32_16x16x32_f16( \
            af[mm], bf[nn], acc[mm][nn], 0, 0, 0);

    // prologue: (0,ks0),(0,ks1),(1,ks0) = 12 loads; gate retires (0,ks0)
    STGA(0, 0) STGB(0, 0) STGA(0, 1) STGB(0, 1) STGA(1, 0) STGB(1, 0)
    asm volatile("s_waitcnt vmcnt(8)" ::: "memory");
    __builtin_amdgcn_s_barrier();

    for (int tt = 0; tt < NT; tt++) {
        int cur = tt & 1;
        bool more = (tt + 1 < NT);
        {   // ---------------- PH0 : kslice 0 ----------------
            half8 af[8], bf[4];
            bf[0] = RDB(0, 0); bf[1] = RDB(1, 0); bf[2] = RDB(2, 0); bf[3] = RDB(3, 0);
            af[0] = RDA(0, 0); af[1] = RDA(1, 0); af[2] = RDA(2, 0); af[3] = RDA(3, 0);
            af[4] = RDA(4, 0); af[5] = RDA(5, 0); af[6] = RDA(6, 0); af[7] = RDA(7, 0);
            if (more) asm volatile("s_waitcnt vmcnt(4)" ::: "memory");  // (tt,ks1) ready
            else      asm volatile("s_waitcnt vmcnt(0)" ::: "memory");
            __builtin_amdgcn_s_barrier();
            if (more) { STGA(tt + 1, 1) STGB(tt + 1, 1) }  // earliest legal issue
            __builtin_amdgcn_s_setprio(1);
            MFMA32()
            __builtin_amdgcn_s_setprio(0);
        }
        {   // ---------------- PH1 : kslice 1 ----------------
            half8 af[8], bf[4];
            bf[0] = RDB(0, 1); bf[1] = RDB(1, 1); bf[2] = RDB(2, 1); bf[3] = RDB(3, 1);
            af[0] = RDA(0, 1); af[1] = RDA(1, 1); af[2] = RDA(2, 1); af[3] = RDA(3, 1);
            af[4] = RDA(4, 1); af[5] = RDA(5, 1); af[6] = RDA(6, 1); af[7] = RDA(7, 1);
            if (more) asm volatile("s_waitcnt vmcnt(4)" ::: "memory");  // (tt+1,ks0) ready
            else      asm volatile("s_waitcnt vmcnt(0)" ::: "memory");
            __builtin_amdgcn_s_barrier();
            if (tt + 2 < NT) { STGA(tt + 2, 0) STGB(tt + 2, 0) }
            __builtin_amdgcn_s_setprio(1);
            MFMA32()
            __builtin_amdgcn_s_setprio(0);
        }
    }

    // ---- epilogue: acc -> LDS (chunk-XOR swizzle) -> coalesced 16B stores ----
    // C/D layout: col=lane&15, row=(lane>>4)*4+reg (m89-verified)
    __builtin_amdgcn_s_barrier();  // all loop LDS reads retired on all waves
    int cr = ls * 4;
#pragma unroll
    for (int i = 0; i < 8; i++) {
#pragma unroll
        for (int j = 0; j < 4; j++) {
#pragma unroll
            for (int r2 = 0; r2 < 4; r2++) {
                int row = wm + i * 16 + cr + r2;
                int col = wn + j * 16 + lm;
                SH[row * 256 + (col ^ ((row & 3) << 3))] = (_Float16)acc[i][j][r2];
            }
        }
    }
    __builtin_amdgcn_s_barrier();
    _Float16* Ch = (_Float16*)Cv;
    int cchunk = t & 31;          // 32 chunks of 8 halves = one 256-col row
    int rbase = t >> 5;           // 16 rows per iteration
#pragma unroll
    for (int it = 0; it < 16; it++) {
        int r = rbase + it * 16;
        half8 v = *(const half8*)&SH[r * 256 + ((cchunk ^ (r & 3)) << 3)];
        *(half8*)&Ch[(long long)(m0 + r) * ldc + n0 + (cchunk << 3) + offC] = v;
    }
#undef STGA
#undef STGB
#undef RDA
#undef RDB
#undef MFMA32
#undef ASX
#undef BSX
}

// ------- Causal softmax, in-place fp16, rows batched over (z',seq) -----------
__global__ __launch_bounds__(256) void softmax_h(_Float16* __restrict__ sc, int S) {
    int wid = threadIdx.x >> 6, lane = threadIdx.x & 63;
    int idx = blockIdx.x * 4 + wid;
    int r = idx & (S - 1);
    _Float16* srow = sc + (long long)idx * S;
    int nc = r >> 9;
    float v[32];
    float mx = -3.0e38f;
    for (int c = 0; c <= nc; c++) {
        half8 hv = *(half8*)(srow + lane * 8 + c * 512);
#pragma unroll
        for (int i = 0; i < 8; i++) {
            int n = lane * 8 + c * 512 + i;
            float s = (n <= r) ? (float)hv[i] : -3.0e38f;
            v[c * 8 + i] = s; mx = fmaxf(mx, s);
        }
    }
#pragma unroll
    for (int off = 32; off; off >>= 1) mx = fmaxf(mx, __shfl_xor(mx, off));
    float sum = 0.f;
    for (int c = 0; c <= nc; c++)
#pragma unroll
        for (int i = 0; i < 8; i++) {
            int n = lane * 8 + c * 512 + i;
            float e = (n <= r) ? __expf(v[c * 8 + i] - mx) : 0.f;
            v[c * 8 + i] = e; sum += e;
        }
#pragma unroll
    for (int off = 32; off; off >>= 1) sum += __shfl_xor(sum, off);
    float inv = 1.f / sum;
    for (int c = 0; c <= nc; c++) {
        half8 o;
#pragma unroll
        for (int i = 0; i < 8; i++) o[i] = (_Float16)(v[c * 8 + i] * inv);
        *(half8*)(srow + lane * 8 + c * 512) = o;
    }
}

extern "C" void kernel_launch(void* const* d_in, const int* in_sizes, int n_in,
                              void* d_out, int out_size, void* d_ws, size_t ws_size,
                              hipStream_t stream) {
    const int B = 4, S = 2048, D = 512, H = 4, U = 1024;
    const float* x     = (const float*)d_in[0];
    const float* gamma = (const float*)d_in[1];
    const float* beta  = (const float*)d_in[2];
    const float* Wq    = (const float*)d_in[3];
    const float* Wk    = (const float*)d_in[4];
    const float* Wv    = (const float*)d_in[5];
    const float* Wout  = (const float*)d_in[6];
    float* out = (float*)d_out;

    char* ws = (char*)d_ws;
    const size_t MiB = 1ull << 20;
    const long long SD = SDo, UD = UDo, SU = SUo, US = USo;

    // W regions must stay adjacent (projQK offB spans WqT..WkT).
    _Float16* xn  = (_Float16*)(ws + 0);         //  8 MiB [B*S, D]
    _Float16* WqT = (_Float16*)(ws + 8  * MiB);  //  4 MiB [H, U, D]
    _Float16* WkT = (_Float16*)(ws + 12 * MiB);  //  4 MiB (adjacent!)
    _Float16* WvT = (_Float16*)(ws + 16 * MiB);  //  4 MiB
    _Float16* WoT = (_Float16*)(ws + 20 * MiB);  //  4 MiB [D, H*U]

    tr_k<<<dim3(U / 32, D / 32, H), dim3(32, 8), 0, stream>>>(Wq, WqT, D, U);
    tr_k<<<dim3(U / 32, D / 32, H), dim3(32, 8), 0, stream>>>(Wk, WkT, D, U);
    tr_k<<<dim3(U / 32, D / 32, H), dim3(32, 8), 0, stream>>>(Wv, WvT, D, U);
    tr_k<<<dim3(D / 32, (H * U) / 32, 1), dim3(32, 8), 0, stream>>>(Wout, WoT, H * U, D);
    ln_k<<<B * S, 64, 0, stream>>>(x, gamma, beta, xn);

    if (ws_size >= 168 * MiB) {
        // ---- pair-batched fast path, peak 152 MiB ----
        _Float16* qk  = (_Float16*)(ws + 24 * MiB);
        _Float16* kk  = qk + 8 * SU;
        _Float16* sc  = (_Float16*)(ws + 88 * MiB);
        _Float16* vt  = qk;
        _Float16* cat = kk;
        float* part   = (float*)(ws + 88 * MiB);  // 32 MiB, reuses dead sc

        for (int p = 0; p < 2; p++) {
            const _Float16* xnp = xn + (long long)p * 2 * SD;
            float* outp = out + (long long)p * 2 * SD;
            // a. projQK: z = qk*8+b2*4+h (16) ; M=S,N=U,K=D
            gemm_bt256<<<dim3(U / 256, S / 256, 16), 512, 0, stream>>>(xnp, WqT, qk, D, U, 0, 1);
            // b. scores: z = h*2+b2 (8) ; M=S,N=S,K=U ; causal skip
            gemm_bt256<<<dim3(S / 256, S / 256, 8), 512, 0, stream>>>(qk, kk, sc, U, S, 4, 2);
            // c. softmax over 8*S rows
            softmax_h<<<8 * S / 4, 256, 0, stream>>>(sc, S);
            // d. projV into q-space: z = h*2+b2 ; M=U,N=S,K=D
            gemm_bt256<<<dim3(S / 256, U / 256, 8), 512, 0, stream>>>(WvT, xnp, vt, D, S, 0, 3);
            // e. PV into k-space: z = h*2+b2 ; M=S,N=U,K=S, kend=m0+256
            gemm_bt256<<<dim3(U / 256, S / 256, 8), 512, 0, stream>>>(sc, vt, cat, S, H * U, 8, 4);
            // f. out pair, SPLIT-K4: M=2S,N=D, K-chunks of 1024, fp32 partials
            //    512 blocks = 2 full GPU rounds (was 128 blocks = half idle)
            gemm_bt<<<dim3(D / 128, 2 * S / 128, 4), 256, 0, stream>>>(cat, WoT, part,
                1024, D, 1, 8, H * U);
            // g. reduce 4 partials -> out (float4 grid-stride)
            redk<<<1024, 256, 0, stream>>>(part, outp, (int)(2 * SD / 4));
        }
    } else {
        // ---- fallback: 96 MiB per-batch (R7 structure) ----
        _Float16* qb   = (_Float16*)(ws + 24 * MiB);
        _Float16* vTb  = (_Float16*)(ws + 56 * MiB);
        _Float16* catb = (_Float16*)(ws + 72 * MiB);
        _Float16* sc   = (_Float16*)(ws + 88 * MiB);

        for (int b = 0; b < B; b++) {
            const _Float16* xnb = xn + (long long)b * SD;
            gemm_bt<<<dim3(U / 128, S / 128, 2 * H), 256, 0, stream>>>(xnb, WqT, qb, D, U, 0, 6, D);
            gemm_bt<<<dim3(S / 128, U / 128, H), 256, 0, stream>>>(WvT, xnb, vTb, D, S, 0, 7, D);
            for (int h = 0; h < H; h++) {
                gemm_bt<<<dim3(S / 128, S / 128, 1), 256, 0, stream>>>(qb + (long long)h * SU,
                    qb + (long long)(H + h) * SU, sc, U, S, 4, 0, U);
                softmax_h<<<S / 4, 256, 0, stream>>>(sc, S);
                gemm_bt<<<dim3(U / 128, S / 128, 1), 256, 0, stream>>>(sc,
                    vTb + (long long)h * US, (void*)(catb + (long long)h * U), S, H * U, 8, 0, S);
            }
            gemm_bt<<<dim3(D / 128, S / 128, 1), 256, 0, stream>>>(catb, WoT,
                (void*)(out + (long long)b * SD), H * U, D, 1, 0, H * U);
        }
    }
}